// Round 3
// baseline (414.047 us; speedup 1.0000x reference)
//
#include <hip/hip_runtime.h>
#include <stdint.h>

// ---------------- Problem constants ----------------
#define T_TOK 8192
#define DDIM  1024
#define NEXP  16
#define MAXTI 208   // 64 shared tiles + worst-case expert tiles

typedef unsigned short u16;
typedef __attribute__((ext_vector_type(8))) short v8s;   // 8 x bf16
typedef __attribute__((ext_vector_type(4))) float v4f;   // 4 x f32 acc

// fp32 -> bf16 round-to-nearest-even
__device__ __forceinline__ u16 f2bf(float f) {
  union { float f; unsigned u; } v; v.f = f;
  unsigned r = v.u + 0x7fffu + ((v.u >> 16) & 1u);
  return (u16)(r >> 16);
}

// async global->LDS, 16B per lane. LDS dest = wave-uniform base + lane*16.
__device__ __forceinline__ void gload_lds16(const u16* gsrc, u16* ldst) {
  typedef __attribute__((address_space(1))) const void GV;
  typedef __attribute__((address_space(3))) void LV;
  __builtin_amdgcn_global_load_lds((GV*)(uintptr_t)gsrc, (LV*)(uintptr_t)ldst, 16, 0, 0);
}

// ---------------- Transposing conversions ----------------
// xbT[kcg=128][tok=8192] 16B chunks: chunk (kcg,tok) = feat[tok][kcg*8 .. +8] in bf16
__global__ __launch_bounds__(256) void k_cvtX(const float* __restrict__ feat,
                                              u16* __restrict__ xbT) {
  int id = blockIdx.x * 256 + threadIdx.x;          // 0 .. 2^20-1
  int tok = id & 8191, kcg = id >> 13;
  const float4* s = (const float4*)(feat + (size_t)tok * DDIM + kcg * 8);
  float4 a = s[0], b = s[1];
  ushort4 o0 = {f2bf(a.x), f2bf(a.y), f2bf(a.z), f2bf(a.w)};
  ushort4 o1 = {f2bf(b.x), f2bf(b.y), f2bf(b.z), f2bf(b.w)};
  ushort4* d = (ushort4*)(xbT + (size_t)id * 8);
  d[0] = o0; d[1] = o1;                              // coalesced writes
}

// wt[(e*8+tileN)*32+kk][kc=4][row=128] 16B chunks:
//   chunk = W[e][tileN*128+row][kk*32 + kc*8 .. +8]
__global__ __launch_bounds__(256) void k_cvtW(const float* __restrict__ ew,
                                              u16* __restrict__ wt) {
  int id = blockIdx.x * 256 + threadIdx.x;          // 0 .. 16*2^17-1
  int row = id & 127, kc = (id >> 7) & 3, kk = (id >> 9) & 31;
  int tileN = (id >> 14) & 7, e = id >> 17;
  const float4* s = (const float4*)(ew + (size_t)e * 1048576 +
                                    (size_t)(tileN * 128 + row) * DDIM + kk * 32 + kc * 8);
  float4 a = s[0], b = s[1];
  ushort4 o0 = {f2bf(a.x), f2bf(a.y), f2bf(a.z), f2bf(a.w)};
  ushort4 o1 = {f2bf(b.x), f2bf(b.y), f2bf(b.z), f2bf(b.w)};
  ushort4* d = (ushort4*)(wt + (size_t)id * 8);
  d[0] = o0; d[1] = o1;
}

// shared expert -> slot e=16 of wt; Wc[h][d] = sw[h][d] + sw[1024+h][d]
__global__ __launch_bounds__(256) void k_cvtS(const float* __restrict__ sw,
                                              u16* __restrict__ wt) {
  int id = blockIdx.x * 256 + threadIdx.x;          // 0 .. 2^17-1
  int row = id & 127, kc = (id >> 7) & 3, kk = (id >> 9) & 31, tileN = (id >> 14) & 7;
  int h = tileN * 128 + row;
  const float4* s0 = (const float4*)(sw + (size_t)h * DDIM + kk * 32 + kc * 8);
  const float4* s1 = (const float4*)(sw + (size_t)(1024 + h) * DDIM + kk * 32 + kc * 8);
  float4 a = s0[0], b = s0[1], c = s1[0], d4 = s1[1];
  ushort4 o0 = {f2bf(a.x + c.x), f2bf(a.y + c.y), f2bf(a.z + c.z), f2bf(a.w + c.w)};
  ushort4 o1 = {f2bf(b.x + d4.x), f2bf(b.y + d4.y), f2bf(b.z + d4.z), f2bf(b.w + d4.w)};
  ushort4* d = (ushort4*)(wt + (size_t)(16 * 131072 + id) * 8);
  d[0] = o0; d[1] = o1;
}

// ---------------- Router (unchanged; verified) ----------------
__global__ __launch_bounds__(256) void k_router(const float* __restrict__ x,
                                                const float* __restrict__ rw,
                                                int* __restrict__ topkI,
                                                float* __restrict__ topkW,
                                                int* __restrict__ counts,
                                                float* __restrict__ piSum) {
  __shared__ float lds_pi[NEXP];
  __shared__ int   lds_cnt[NEXP];
  int tid = threadIdx.x;
  if (tid < NEXP) { lds_pi[tid] = 0.f; lds_cnt[tid] = 0; }
  __syncthreads();
  int lane = tid & 63, wave = tid >> 6;

  for (int ti = 0; ti < 8; ++ti) {
    int t = blockIdx.x * 32 + wave * 8 + ti;
    const float* xr = x + (size_t)t * DDIM;
    float xv[16];
#pragma unroll
    for (int i = 0; i < 16; ++i) xv[i] = xr[i * 64 + lane];
    float lg[NEXP];
#pragma unroll
    for (int e = 0; e < NEXP; ++e) {
      const float* wr = rw + (size_t)e * DDIM;
      float p = 0.f;
#pragma unroll
      for (int i = 0; i < 16; ++i) p += xv[i] * wr[i * 64 + lane];
#pragma unroll
      for (int off = 32; off > 0; off >>= 1) p += __shfl_xor(p, off);
      lg[e] = p;
    }
    float mx = lg[0];
#pragma unroll
    for (int e = 1; e < NEXP; ++e) mx = fmaxf(mx, lg[e]);
    float sum = 0.f;
#pragma unroll
    for (int e = 0; e < NEXP; ++e) sum += __expf(lg[e] - mx);
    float v0 = lg[0]; int i0 = 0;
#pragma unroll
    for (int e = 1; e < NEXP; ++e) if (lg[e] > v0) { v0 = lg[e]; i0 = e; }
    float v1 = -3.0e38f; int i1 = 0;
#pragma unroll
    for (int e = 0; e < NEXP; ++e) if (e != i0 && lg[e] > v1) { v1 = lg[e]; i1 = e; }
    float e1 = __expf(v1 - v0);
    float w0 = 1.f / (1.f + e1);
    float w1 = e1 / (1.f + e1);
    if (lane == 0) {
      topkI[2 * t] = i0; topkI[2 * t + 1] = i1;
      topkW[2 * t] = w0; topkW[2 * t + 1] = w1;
      atomicAdd(&lds_cnt[i0], 1); atomicAdd(&lds_cnt[i1], 1);
    }
#pragma unroll
    for (int e = 0; e < NEXP; ++e)
      if (lane == e) atomicAdd(&lds_pi[e], __expf(lg[e] - mx) / sum);
  }
  __syncthreads();
  if (tid < NEXP) {
    atomicAdd(&counts[tid], lds_cnt[tid]);
    atomicAdd(&piSum[tid], lds_pi[tid]);
  }
}

// ---------------- Finalize: wave-parallel prefix scans + aux ----------------
__global__ void k_finalize(const int* __restrict__ counts, const float* __restrict__ piSum,
                           int* __restrict__ offs, int* __restrict__ tileStart,
                           int* __restrict__ cursor, float* __restrict__ outAux) {
  int lane = threadIdx.x;                 // 64 threads = 1 wave
  int c = (lane < NEXP) ? counts[lane] : 0;
  float p = (lane < NEXP) ? piSum[lane] : 0.f;
  int tc = (c + 127) >> 7;
  int ic = c, itc = tc;
  for (int d = 1; d < NEXP; d <<= 1) {
    int v1 = __shfl_up(ic, d), v2 = __shfl_up(itc, d);
    if (lane >= d) { ic += v1; itc += v2; }
  }
  if (lane < NEXP) {
    offs[lane] = ic - c;
    tileStart[lane] = 64 + itc - tc;
    cursor[lane] = 0;
    if (lane == NEXP - 1) { offs[NEXP] = ic; tileStart[NEXP] = 64 + itc; }
  }
  float term = (lane < NEXP) ? (p / (float)T_TOK) * ((float)c / (float)T_TOK) : 0.f;
  for (int off = 8; off; off >>= 1) term += __shfl_xor(term, off);
  if (lane == 0) outAux[0] = term;
}

// ---------------- Scatter token-expert pairs into buckets ----------------
__global__ __launch_bounds__(256) void k_scatter(const int* __restrict__ topkI,
                                                 const float* __restrict__ topkW,
                                                 const int* __restrict__ offs,
                                                 int* __restrict__ cursor,
                                                 int* __restrict__ rowTok,
                                                 float* __restrict__ rowW) {
  __shared__ int lcnt[NEXP], lbase[NEXP];
  int tid = threadIdx.x;
  if (tid < NEXP) lcnt[tid] = 0;
  __syncthreads();
  int p = blockIdx.x * 256 + tid;
  int e = topkI[p];
  int myLocal = atomicAdd(&lcnt[e], 1);
  __syncthreads();
  if (tid < NEXP) lbase[tid] = atomicAdd(&cursor[tid], lcnt[tid]);
  __syncthreads();
  int dst = offs[e] + lbase[e] + myLocal;
  rowTok[dst] = p >> 1;
  rowW[dst] = topkW[p];
}

// ---------------- Fused grouped GEMM: 128x128, BK=32, 2-phase ----------------
// LDS tile (16B units): slot = kc*128 + row (kc 0..3). Staged LINEARLY from the
// pre-transposed buffers -> B staging is one contiguous 8KB stream, A staging is
// per-kc-plane contiguous (shared) / gathered (experts). Reader lanes 0..15 read
// 256B contiguous -> 2 lanes/bank -> conflict-free.
// grid = (tileN=8, ti): linear id % 8 == tileN -> each XCD owns one col-block.
__global__ __launch_bounds__(256, 4) void k_gemm(const u16* __restrict__ xbT,
                                                 const u16* __restrict__ wt,
                                                 const int* __restrict__ tileStart,
                                                 const int* __restrict__ offs,
                                                 const int* __restrict__ rowTok,
                                                 const float* __restrict__ rowW,
                                                 float* __restrict__ out) {
  __shared__ u16 As[2][4096];
  __shared__ u16 Bs[2][4096];
  int tid = threadIdx.x;
  int tileN = blockIdx.x;                 // 0..7
  int ti = blockIdx.y;
  if (ti >= tileStart[NEXP]) return;

  int e, rowStart, offBase = 0, cnt;
  if (ti < 64) { e = NEXP; rowStart = ti * 128; cnt = T_TOK; }
  else {
    e = 0;
    while (ti >= tileStart[e + 1]) ++e;
    rowStart = (ti - tileStart[e]) * 128;
    offBase = offs[e]; cnt = offs[e + 1] - offBase;
  }

  int lane = tid & 63, wave = tid >> 6;
  int srow = tid & 127;                   // tile-local row staged by this thread
  int kcLo = tid >> 7;                    // 0 or 1 (second load does kcLo+2)
  int tok;
  if (e == NEXP) tok = rowStart + srow;
  else tok = rowTok[offBase + min(rowStart + srow, cnt - 1)];
  const u16* aBase = xbT + (size_t)tok * 8;                       // + plane*65536
  const u16* wTile = wt + (size_t)(e * 8 + tileN) * 32 * 4096;    // + kk*4096

  v4f acc[4][4];
#pragma unroll
  for (int m = 0; m < 4; ++m)
#pragma unroll
    for (int n = 0; n < 4; ++n) acc[m][n] = (v4f)0.f;

  int wm = (wave >> 1) * 64, wn = (wave & 1) * 64;
  int rsel = lane & 15;
  int q = lane >> 4;

#define STAGE(buf, kk)                                                          \
  do {                                                                          \
    gload_lds16(aBase + (size_t)((kk) * 4 + kcLo) * 65536,                      \
                &As[buf][wave * 512]);                                          \
    gload_lds16(aBase + (size_t)((kk) * 4 + kcLo + 2) * 65536,                  \
                &As[buf][2048 + wave * 512]);                                   \
    gload_lds16(wTile + (size_t)(kk) * 4096 + tid * 8, &Bs[buf][wave * 512]);   \
    gload_lds16(wTile + (size_t)(kk) * 4096 + (tid + 256) * 8,                  \
                &Bs[buf][2048 + wave * 512]);                                   \
  } while (0)

  STAGE(0, 0);
  __syncthreads();

  int cur = 0;
  for (int t = 0; t < 32; ++t) {
    if (t + 1 < 32) STAGE(cur ^ 1, t + 1);

    v8s af[4], bfr[4];
#pragma unroll
    for (int m = 0; m < 4; ++m)
      af[m] = *(const v8s*)&As[cur][(q * 128 + wm + m * 16 + rsel) * 8];
#pragma unroll
    for (int n = 0; n < 4; ++n)
      bfr[n] = *(const v8s*)&Bs[cur][(q * 128 + wn + n * 16 + rsel) * 8];
#pragma unroll
    for (int m = 0; m < 4; ++m)
#pragma unroll
      for (int n = 0; n < 4; ++n)
        acc[m][n] = __builtin_amdgcn_mfma_f32_16x16x32_bf16(af[m], bfr[n], acc[m][n], 0, 0, 0);

    __syncthreads();
    cur ^= 1;
  }
#undef STAGE

  // epilogue: C/D layout col=lane&15, row=(lane>>4)*4+j; out pre-zeroed -> atomicAdd
  int colBase = tileN * 128 + wn + rsel;
#pragma unroll
  for (int m = 0; m < 4; ++m) {
    int rloc = rowStart + wm + m * 16 + q * 4;
#pragma unroll
    for (int j = 0; j < 4; ++j) {
      int r = rloc + j;
      if (r < cnt) {
        int t; float w;
        if (e == NEXP) { t = r; w = 1.f; }
        else { t = rowTok[offBase + r]; w = rowW[offBase + r]; }
        float* orow = out + (size_t)t * DDIM;
#pragma unroll
        for (int n = 0; n < 4; ++n)
          atomicAdd(orow + colBase + n * 16, w * acc[m][n][j]);
      }
    }
  }
}

// ---------------- launch ----------------
extern "C" void kernel_launch(void* const* d_in, const int* in_sizes, int n_in,
                              void* d_out, int out_size, void* d_ws, size_t ws_size,
                              hipStream_t stream) {
  const float* feat = (const float*)d_in[0];  // [8192][1024]
  const float* rw   = (const float*)d_in[1];  // [16][1024]
  const float* sw   = (const float*)d_in[2];  // [2048][1024]
  const float* ew   = (const float*)d_in[3];  // [16][1024][1024]
  float* out = (float*)d_out;                 // [8192*1024] + aux at [8388608]
  char* ws = (char*)d_ws;

  // ws layout (~52.7 MB)
  u16* xbT = (u16*)(ws + 0);                  // 16 MB  (transposed activations)
  u16* wt  = (u16*)(ws + 16777216);           // 17 x 2 MB (tiled weights)
  char* smallBase = ws + 52428800;
  int*   counts    = (int*)(smallBase + 0);
  float* piSum     = (float*)(smallBase + 64);
  int*   cursor    = (int*)(smallBase + 128);
  int*   offs      = (int*)(smallBase + 192);   // 17 ints
  int*   tileStart = (int*)(smallBase + 320);   // 17 ints
  int*   topkI  = (int*)(ws + 52429824);
  float* topkW  = (float*)(ws + 52495360);
  int*   rowTok = (int*)(ws + 52560896);
  float* rowW   = (float*)(ws + 52626432);

  hipMemsetAsync(smallBase, 0, 192, stream);
  hipMemsetAsync(out, 0, (size_t)out_size * sizeof(float), stream);

  k_cvtX<<<4096, 256, 0, stream>>>(feat, xbT);
  k_cvtW<<<8192, 256, 0, stream>>>(ew, wt);
  k_cvtS<<<512, 256, 0, stream>>>(sw, wt);

  k_router<<<256, 256, 0, stream>>>(feat, rw, topkI, topkW, counts, piSum);
  k_finalize<<<1, 64, 0, stream>>>(counts, piSum, offs, tileStart, cursor, out + 8388608);
  k_scatter<<<64, 256, 0, stream>>>(topkI, topkW, offs, cursor, rowTok, rowW);

  dim3 gGemm(8, MAXTI);
  k_gemm<<<gGemm, 256, 0, stream>>>(xbT, wt, tileStart, offs, rowTok, rowW, out);
}

// Round 4
// 406.985 us; speedup vs baseline: 1.0174x; 1.0174x over previous
//
#include <hip/hip_runtime.h>
#include <stdint.h>

// ---------------- Problem constants ----------------
#define T_TOK 8192
#define DDIM  1024
#define NEXP  16
#define MAXTI 208   // 64 shared tiles + worst-case expert tiles (<= 207)

typedef unsigned short u16;
typedef __attribute__((ext_vector_type(8))) short v8s;   // 8 x bf16
typedef __attribute__((ext_vector_type(4))) float v4f;   // 4 x f32 acc

// fp32 -> bf16 round-to-nearest-even
__device__ __forceinline__ u16 f2bf(float f) {
  union { float f; unsigned u; } v; v.f = f;
  unsigned r = v.u + 0x7fffu + ((v.u >> 16) & 1u);
  return (u16)(r >> 16);
}

// async global->LDS, 16B per lane. LDS dest = wave-uniform base + lane*16.
__device__ __forceinline__ void gload_lds16(const u16* gsrc, u16* ldst) {
  typedef __attribute__((address_space(1))) const void GV;
  typedef __attribute__((address_space(3))) void LV;
  __builtin_amdgcn_global_load_lds((GV*)(uintptr_t)gsrc, (LV*)(uintptr_t)ldst, 16, 0, 0);
}

// ---------------- Coalesced transposing conversions (through LDS) ----------------
// Both kernels: 256 threads, read 4 float4/thread with lane-contiguous 128B row
// segments (rows 4KB apart -> 2 full lines per row, coalesced), transpose to
// chunk-major bf16 in LDS, write out linearly.

// feat[8192][1024] f32 -> xbT: chunk idx = plane*8192 + tok, plane = kcg 0..127
// block b: tb = b&63 (128-token block), kk = b>>6 (0..31, 32-float K-slab)
__global__ __launch_bounds__(256) void k_cvtA(const float* __restrict__ feat,
                                              u16* __restrict__ xbT) {
  __shared__ u16 lds[4096];
  int b = blockIdx.x;
  int tb = b & 63, kk = b >> 6;
  int tid = threadIdx.x;
  int frow = tid >> 3, fcol = tid & 7;
#pragma unroll
  for (int p = 0; p < 4; ++p) {
    int row = frow + p * 32;
    float4 v = *(const float4*)(feat + (size_t)(tb * 128 + row) * DDIM + kk * 32 + fcol * 4);
    ushort4 o = {f2bf(v.x), f2bf(v.y), f2bf(v.z), f2bf(v.w)};
    *(ushort4*)&lds[((fcol >> 1) * 128 + row) * 8 + (fcol & 1) * 4] = o;
  }
  __syncthreads();
#pragma unroll
  for (int i = 0; i < 2; ++i) {
    int s = tid + i * 256;                       // chunk slot: kc = s>>7, row = s&127
    u16* dst = xbT + ((size_t)(kk * 4 + (s >> 7)) * 8192 + tb * 128 + (s & 127)) * 8;
    *(float4*)dst = *(float4*)&lds[s * 8];
  }
}

// ew[16][1024][1024] (+ shared fold at e==16) -> wt[(e*8+tileN)*32+kk][kc][row]
// block b: kk = b&31, tileN = (b>>5)&7, e = b>>8 (0..16)
__global__ __launch_bounds__(256) void k_cvtB(const float* __restrict__ ew,
                                              const float* __restrict__ sw,
                                              u16* __restrict__ wt) {
  __shared__ u16 lds[4096];
  int b = blockIdx.x;
  int kk = b & 31, tileN = (b >> 5) & 7, e = b >> 8;
  int tid = threadIdx.x;
  int frow = tid >> 3, fcol = tid & 7;
#pragma unroll
  for (int p = 0; p < 4; ++p) {
    int row = frow + p * 32;
    float4 v;
    if (e < NEXP) {
      v = *(const float4*)(ew + ((size_t)e << 20) + (size_t)(tileN * 128 + row) * DDIM +
                           kk * 32 + fcol * 4);
    } else {
      int h = tileN * 128 + row;
      float4 a = *(const float4*)(sw + (size_t)h * DDIM + kk * 32 + fcol * 4);
      float4 c = *(const float4*)(sw + (size_t)(1024 + h) * DDIM + kk * 32 + fcol * 4);
      v = make_float4(a.x + c.x, a.y + c.y, a.z + c.z, a.w + c.w);
    }
    ushort4 o = {f2bf(v.x), f2bf(v.y), f2bf(v.z), f2bf(v.w)};
    *(ushort4*)&lds[((fcol >> 1) * 128 + row) * 8 + (fcol & 1) * 4] = o;
  }
  __syncthreads();
  u16* dst = wt + (size_t)((e * 8 + tileN) * 32 + kk) * 4096;
#pragma unroll
  for (int i = 0; i < 2; ++i) {
    int s = tid + i * 256;
    *(float4*)&dst[s * 8] = *(float4*)&lds[s * 8];
  }
}

// ---------------- Router (unchanged; verified) ----------------
__global__ __launch_bounds__(256) void k_router(const float* __restrict__ x,
                                                const float* __restrict__ rw,
                                                int* __restrict__ topkI,
                                                float* __restrict__ topkW,
                                                int* __restrict__ counts,
                                                float* __restrict__ piSum) {
  __shared__ float lds_pi[NEXP];
  __shared__ int   lds_cnt[NEXP];
  int tid = threadIdx.x;
  if (tid < NEXP) { lds_pi[tid] = 0.f; lds_cnt[tid] = 0; }
  __syncthreads();
  int lane = tid & 63, wave = tid >> 6;

  for (int ti = 0; ti < 8; ++ti) {
    int t = blockIdx.x * 32 + wave * 8 + ti;
    const float* xr = x + (size_t)t * DDIM;
    float xv[16];
#pragma unroll
    for (int i = 0; i < 16; ++i) xv[i] = xr[i * 64 + lane];
    float lg[NEXP];
#pragma unroll
    for (int e = 0; e < NEXP; ++e) {
      const float* wr = rw + (size_t)e * DDIM;
      float p = 0.f;
#pragma unroll
      for (int i = 0; i < 16; ++i) p += xv[i] * wr[i * 64 + lane];
#pragma unroll
      for (int off = 32; off > 0; off >>= 1) p += __shfl_xor(p, off);
      lg[e] = p;
    }
    float mx = lg[0];
#pragma unroll
    for (int e = 1; e < NEXP; ++e) mx = fmaxf(mx, lg[e]);
    float sum = 0.f;
#pragma unroll
    for (int e = 0; e < NEXP; ++e) sum += __expf(lg[e] - mx);
    float v0 = lg[0]; int i0 = 0;
#pragma unroll
    for (int e = 1; e < NEXP; ++e) if (lg[e] > v0) { v0 = lg[e]; i0 = e; }
    float v1 = -3.0e38f; int i1 = 0;
#pragma unroll
    for (int e = 0; e < NEXP; ++e) if (e != i0 && lg[e] > v1) { v1 = lg[e]; i1 = e; }
    float e1 = __expf(v1 - v0);
    float w0 = 1.f / (1.f + e1);
    float w1 = e1 / (1.f + e1);
    if (lane == 0) {
      topkI[2 * t] = i0; topkI[2 * t + 1] = i1;
      topkW[2 * t] = w0; topkW[2 * t + 1] = w1;
      atomicAdd(&lds_cnt[i0], 1); atomicAdd(&lds_cnt[i1], 1);
    }
#pragma unroll
    for (int e = 0; e < NEXP; ++e)
      if (lane == e) atomicAdd(&lds_pi[e], __expf(lg[e] - mx) / sum);
  }
  __syncthreads();
  if (tid < NEXP) {
    atomicAdd(&counts[tid], lds_cnt[tid]);
    atomicAdd(&piSum[tid], lds_pi[tid]);
  }
}

// ---------------- Finalize: wave-parallel prefix scans + aux ----------------
__global__ void k_finalize(const int* __restrict__ counts, const float* __restrict__ piSum,
                           int* __restrict__ offs, int* __restrict__ tileStart,
                           int* __restrict__ cursor, float* __restrict__ outAux) {
  int lane = threadIdx.x;                 // 64 threads = 1 wave
  int c = (lane < NEXP) ? counts[lane] : 0;
  float p = (lane < NEXP) ? piSum[lane] : 0.f;
  int tc = (c + 127) >> 7;
  int ic = c, itc = tc;
  for (int d = 1; d < NEXP; d <<= 1) {
    int v1 = __shfl_up(ic, d), v2 = __shfl_up(itc, d);
    if (lane >= d) { ic += v1; itc += v2; }
  }
  if (lane < NEXP) {
    offs[lane] = ic - c;
    tileStart[lane] = 64 + itc - tc;
    cursor[lane] = 0;
    if (lane == NEXP - 1) { offs[NEXP] = ic; tileStart[NEXP] = 64 + itc; }
  }
  float term = (lane < NEXP) ? (p / (float)T_TOK) * ((float)c / (float)T_TOK) : 0.f;
  for (int off = 8; off; off >>= 1) term += __shfl_xor(term, off);
  if (lane == 0) outAux[0] = term;
}

// ---------------- Scatter token-expert pairs into buckets ----------------
__global__ __launch_bounds__(256) void k_scatter(const int* __restrict__ topkI,
                                                 const float* __restrict__ topkW,
                                                 const int* __restrict__ offs,
                                                 int* __restrict__ cursor,
                                                 int* __restrict__ rowTok,
                                                 float* __restrict__ rowW) {
  __shared__ int lcnt[NEXP], lbase[NEXP];
  int tid = threadIdx.x;
  if (tid < NEXP) lcnt[tid] = 0;
  __syncthreads();
  int p = blockIdx.x * 256 + tid;
  int e = topkI[p];
  int myLocal = atomicAdd(&lcnt[e], 1);
  __syncthreads();
  if (tid < NEXP) lbase[tid] = atomicAdd(&cursor[tid], lcnt[tid]);
  __syncthreads();
  int dst = offs[e] + lbase[e] + myLocal;
  rowTok[dst] = p >> 1;
  rowW[dst] = topkW[p];
}

// ---------------- Fused grouped GEMM: 128x128, BK=32, counted-vmcnt pipeline ----
// LDS tile (16B units): slot = kc*128 + row. Reader 16-lane groups read 256B
// contiguous -> conflict-free (verified 0 conflicts R2/R3).
// Pipeline: 2 LDS buffers, 2 tiles in flight, vmcnt(4) per iter (never 0 in loop),
// raw s_barrier (no implicit vmcnt drain, unlike __syncthreads).
__global__ __launch_bounds__(256, 4) void k_gemm(const u16* __restrict__ xbT,
                                                 const u16* __restrict__ wt,
                                                 const int* __restrict__ tileStart,
                                                 const int* __restrict__ offs,
                                                 const int* __restrict__ rowTok,
                                                 const float* __restrict__ rowW,
                                                 float* __restrict__ out) {
  __shared__ u16 As[2][4096];
  __shared__ u16 Bs[2][4096];
  int tid = threadIdx.x;
  int tileN = blockIdx.x;                 // 0..7 -> XCD affinity
  int ti = blockIdx.y;
  if (ti >= tileStart[NEXP]) return;

  int e, rowStart, offBase = 0, cnt;
  if (ti < 64) { e = NEXP; rowStart = ti * 128; cnt = T_TOK; }
  else {
    e = 0;
    while (ti >= tileStart[e + 1]) ++e;
    rowStart = (ti - tileStart[e]) * 128;
    offBase = offs[e]; cnt = offs[e + 1] - offBase;
  }

  int lane = tid & 63, wave = tid >> 6;
  int srow = tid & 127;                   // tile-local row staged by this thread
  int kcLo = tid >> 7;                    // 0 or 1 (second load does kcLo+2)
  int tok;
  if (e == NEXP) tok = rowStart + srow;
  else tok = rowTok[offBase + min(rowStart + srow, cnt - 1)];
  const u16* aBase = xbT + (size_t)tok * 8;                       // + plane*65536
  const u16* wTile = wt + (size_t)(e * 8 + tileN) * 32 * 4096;    // + kk*4096

  v4f acc[4][4];
#pragma unroll
  for (int m = 0; m < 4; ++m)
#pragma unroll
    for (int n = 0; n < 4; ++n) acc[m][n] = (v4f)0.f;

  int wm = (wave >> 1) * 64, wn = (wave & 1) * 64;
  int rsel = lane & 15;
  int q = lane >> 4;

#define STAGE(buf, kk)                                                          \
  do {                                                                          \
    gload_lds16(aBase + (size_t)((kk) * 4 + kcLo) * 65536,                      \
                &As[buf][wave * 512]);                                          \
    gload_lds16(aBase + (size_t)((kk) * 4 + kcLo + 2) * 65536,                  \
                &As[buf][2048 + wave * 512]);                                   \
    gload_lds16(wTile + (size_t)(kk) * 4096 + tid * 8, &Bs[buf][wave * 512]);   \
    gload_lds16(wTile + (size_t)(kk) * 4096 + (tid + 256) * 8,                  \
                &Bs[buf][2048 + wave * 512]);                                   \
  } while (0)

#define LOADFRAGS(buf)                                                          \
  do {                                                                          \
    _Pragma("unroll")                                                           \
    for (int m = 0; m < 4; ++m)                                                 \
      af[m] = *(const v8s*)&As[buf][(q * 128 + wm + m * 16 + rsel) * 8];        \
    _Pragma("unroll")                                                           \
    for (int n = 0; n < 4; ++n)                                                 \
      bfr[n] = *(const v8s*)&Bs[buf][(q * 128 + wn + n * 16 + rsel) * 8];       \
  } while (0)

#define DOMFMA                                                                  \
  do {                                                                          \
    _Pragma("unroll")                                                           \
    for (int m = 0; m < 4; ++m)                                                 \
      _Pragma("unroll")                                                         \
      for (int n = 0; n < 4; ++n)                                               \
        acc[m][n] = __builtin_amdgcn_mfma_f32_16x16x32_bf16(af[m], bfr[n],      \
                                                            acc[m][n], 0, 0, 0);\
  } while (0)

  v8s af[4], bfr[4];

  // prologue: 2 tiles in flight (8 loads/thread)
  STAGE(0, 0);
  STAGE(1, 1);

  int cur = 0;
  for (int t = 0; t < 31; ++t) {
    // tile t landed (4 newest loads -- tile t+1 -- may still fly)
    asm volatile("s_waitcnt vmcnt(4)" ::: "memory");
    __builtin_amdgcn_s_barrier();          // all waves' tile-t loads landed
    __builtin_amdgcn_sched_barrier(0);
    LOADFRAGS(cur);
    asm volatile("s_waitcnt lgkmcnt(0)" ::: "memory");
    __builtin_amdgcn_sched_barrier(0);
    __builtin_amdgcn_s_barrier();          // all waves done reading buf[cur]
    __builtin_amdgcn_sched_barrier(0);
    if (t < 30) STAGE(cur, t + 2);         // refill freed buffer; stays in flight
    __builtin_amdgcn_s_setprio(1);
    DOMFMA;
    __builtin_amdgcn_s_setprio(0);
    cur ^= 1;
  }
  // final tile (31): drain
  asm volatile("s_waitcnt vmcnt(0)" ::: "memory");
  __builtin_amdgcn_s_barrier();
  __builtin_amdgcn_sched_barrier(0);
  LOADFRAGS(cur);
  asm volatile("s_waitcnt lgkmcnt(0)" ::: "memory");
  __builtin_amdgcn_sched_barrier(0);
  DOMFMA;

#undef STAGE
#undef LOADFRAGS
#undef DOMFMA

  // epilogue: C/D layout col=lane&15, row=(lane>>4)*4+j; out pre-zeroed -> atomicAdd
  int colBase = tileN * 128 + wn + rsel;
#pragma unroll
  for (int m = 0; m < 4; ++m) {
    int rloc = rowStart + wm + m * 16 + q * 4;
#pragma unroll
    for (int j = 0; j < 4; ++j) {
      int r = rloc + j;
      if (r < cnt) {
        int t; float w;
        if (e == NEXP) { t = r; w = 1.f; }
        else { t = rowTok[offBase + r]; w = rowW[offBase + r]; }
        float* orow = out + (size_t)t * DDIM;
#pragma unroll
        for (int n = 0; n < 4; ++n)
          atomicAdd(orow + colBase + n * 16, w * acc[m][n][j]);
      }
    }
  }
}

// ---------------- launch ----------------
extern "C" void kernel_launch(void* const* d_in, const int* in_sizes, int n_in,
                              void* d_out, int out_size, void* d_ws, size_t ws_size,
                              hipStream_t stream) {
  const float* feat = (const float*)d_in[0];  // [8192][1024]
  const float* rw   = (const float*)d_in[1];  // [16][1024]
  const float* sw   = (const float*)d_in[2];  // [2048][1024]
  const float* ew   = (const float*)d_in[3];  // [16][1024][1024]
  float* out = (float*)d_out;                 // [8192*1024] + aux at [8388608]
  char* ws = (char*)d_ws;

  // ws layout (~52.7 MB)
  u16* xbT = (u16*)(ws + 0);                  // 16 MB  (plane-major activations)
  u16* wt  = (u16*)(ws + 16777216);           // 17 x 2 MB (tile-transposed weights)
  char* smallBase = ws + 52428800;
  int*   counts    = (int*)(smallBase + 0);
  float* piSum     = (float*)(smallBase + 64);
  int*   cursor    = (int*)(smallBase + 128);
  int*   offs      = (int*)(smallBase + 192);   // 17 ints
  int*   tileStart = (int*)(smallBase + 320);   // 17 ints
  int*   topkI  = (int*)(ws + 52429824);
  float* topkW  = (float*)(ws + 52495360);
  int*   rowTok = (int*)(ws + 52560896);
  float* rowW   = (float*)(ws + 52626432);

  hipMemsetAsync(smallBase, 0, 192, stream);
  hipMemsetAsync(out, 0, (size_t)out_size * sizeof(float), stream);

  k_cvtA<<<2048, 256, 0, stream>>>(feat, xbT);
  k_cvtB<<<4352, 256, 0, stream>>>(ew, sw, wt);

  k_router<<<256, 256, 0, stream>>>(feat, rw, topkI, topkW, counts, piSum);
  k_finalize<<<1, 64, 0, stream>>>(counts, piSum, offs, tileStart, cursor, out + 8388608);
  k_scatter<<<64, 256, 0, stream>>>(topkI, topkW, offs, cursor, rowTok, rowW);

  dim3 gGemm(8, MAXTI);
  k_gemm<<<gGemm, 256, 0, stream>>>(xbT, wt, tileStart, offs, rowTok, rowW, out);
}